// Round 3
// baseline (250.464 us; speedup 1.0000x reference)
//
#include <hip/hip_runtime.h>
#include <stdint.h>

typedef short bf16x8 __attribute__((ext_vector_type(8)));
typedef float f32x4 __attribute__((ext_vector_type(4)));

#define DEV __device__ __forceinline__

static constexpr int BB = 2, NN = 2048, DD = 1024, HH = 16, DH = 64;
static constexpr float SCLOG2E = 0.18033688011112042f; // DH^-0.5 * log2(e)

// ---- workspace layout (bytes) ----
static constexpr size_t OFF_PACK   = 1024;
static constexpr size_t PACK_BYTES = (size_t)BB * NN * (NN / 64) * 8ull; // 1MB
static constexpr size_t OFF_WT     = OFF_PACK + PACK_BYTES;
static constexpr size_t WT_ONE     = (size_t)DD * DD;
static constexpr size_t HEAD_BYTES = (size_t)BB * HH * NN * DH * 2ull;   // 8MB
static constexpr size_t OFF_QH     = OFF_WT + 4 * WT_ONE * 2;
static constexpr size_t OFF_KH     = OFF_QH + HEAD_BYTES;
static constexpr size_t OFF_VT     = OFF_KH + HEAD_BYTES;
static constexpr size_t OFF_X      = OFF_VT + HEAD_BYTES;
static constexpr size_t OFF_KB     = OFF_X + HEAD_BYTES;
static constexpr size_t OFF_VB     = OFF_KB + HEAD_BYTES;
static constexpr size_t NEED_BIG   = OFF_VB + HEAD_BYTES;   // ~59.8MB

DEV unsigned short f2b(float f) {                  // fp32 -> bf16 RNE
  unsigned int u = __builtin_bit_cast(unsigned int, f);
  u = (u + 0x7fffu + ((u >> 16) & 1u)) >> 16;
  return (unsigned short)u;
}

#define GLOAD16(gp, lp) __builtin_amdgcn_global_load_lds(                     \
    (const __attribute__((address_space(1))) void*)(gp),                      \
    (__attribute__((address_space(3))) void*)(lp), 16, 0, 0)

// ---------------- mask dtype detection ----------------
__global__ void detect_mask(const unsigned int* m, unsigned int* flag) {
  int t = threadIdx.x;
  uint4 v = ((const uint4*)m)[t];
  unsigned int vals[4] = {v.x, v.y, v.z, v.w};
  unsigned int f = 0;
  for (int i = 0; i < 4; i++) {
    unsigned int x = vals[i];
    if (x != 0u && x != 1u) f |= 1u;
    if (x != 0u && x != 0x3f800000u) f |= 2u;
  }
  if (f) atomicOr(flag, f);
}

// ---------------- mask packing: 1 bit per entry ----------------
__global__ void pack_mask(const void* msrc, const unsigned int* flag,
                          unsigned long long* packed) {
  int w = blockIdx.x * 256 + threadIdx.x;
  unsigned int f = *flag;
  size_t base = (size_t)(w >> 5) * 2048 + (size_t)(w & 31) * 64;
  unsigned long long bits = 0ull;
  if (!(f & 1u)) {                                 // int32 storage
    const int4* p = (const int4*)msrc + (base >> 2);
    #pragma unroll
    for (int c = 0; c < 16; c++) {
      int4 q = p[c];
      if (q.x) bits |= 1ull << (4 * c + 0);
      if (q.y) bits |= 1ull << (4 * c + 1);
      if (q.z) bits |= 1ull << (4 * c + 2);
      if (q.w) bits |= 1ull << (4 * c + 3);
    }
  } else if (!(f & 2u)) {                          // float32 storage
    const float4* p = (const float4*)msrc + (base >> 2);
    #pragma unroll
    for (int c = 0; c < 16; c++) {
      float4 q = p[c];
      if (q.x != 0.f) bits |= 1ull << (4 * c + 0);
      if (q.y != 0.f) bits |= 1ull << (4 * c + 1);
      if (q.z != 0.f) bits |= 1ull << (4 * c + 2);
      if (q.w != 0.f) bits |= 1ull << (4 * c + 3);
    }
  } else {                                         // uint8/bool storage
    const uint4* p = (const uint4*)((const char*)msrc + base);
    #pragma unroll
    for (int c = 0; c < 4; c++) {
      uint4 q = p[c];
      unsigned int vals[4] = {q.x, q.y, q.z, q.w};
      #pragma unroll
      for (int i = 0; i < 4; i++)
        #pragma unroll
        for (int j = 0; j < 4; j++)
          if ((vals[i] >> (8 * j)) & 0xffu) bits |= 1ull << (16 * c + 4 * i + j);
    }
  }
  packed[w] = bits;
}

// ---------------- weight transpose: W[k][n] f32 -> Wt[n][k] bf16 ----------------
__global__ void transpose_w(const float* W0, const float* W1, const float* W2,
                            const float* W3, unsigned short* wt) {
  __shared__ unsigned short T[64][72];
  int z = blockIdx.z, t = threadIdx.x;
  const float* W = (z == 0) ? W0 : (z == 1) ? W1 : (z == 2) ? W2 : W3;
  unsigned short* dst = wt + (size_t)z * WT_ONE;
  int k0 = blockIdx.y * 64, n0 = blockIdx.x * 64;
  #pragma unroll
  for (int i = 0; i < 4; i++) {
    int row = i * 16 + (t >> 4), col = 4 * (t & 15);
    float4 v = *(const float4*)&W[(size_t)(k0 + row) * DD + n0 + col];
    T[row][col + 0] = f2b(v.x); T[row][col + 1] = f2b(v.y);
    T[row][col + 2] = f2b(v.z); T[row][col + 3] = f2b(v.w);
  }
  __syncthreads();
  #pragma unroll
  for (int i = 0; i < 4; i++) {
    int n = i * 16 + (t >> 4), k = 4 * (t & 15);
    ushort4 o = make_ushort4(T[k][n], T[k + 1][n], T[k + 2][n], T[k + 3][n]);
    *(ushort4*)&dst[(size_t)(n0 + n) * DD + k0 + k] = o;
  }
}

// ---------------- fp32 -> bf16 convert for q,k,v ----------------
__global__ void cvt_qkv(const float* q, const float* k, const float* v,
                        unsigned short* qb, unsigned short* kb,
                        unsigned short* vb) {
  int z = blockIdx.z;
  const float* s = (z == 0) ? q : (z == 1) ? k : v;
  unsigned short* d = (z == 0) ? qb : (z == 1) ? kb : vb;
  size_t i = ((size_t)blockIdx.x * 256 + threadIdx.x) * 8;
  float4 a = *(const float4*)&s[i];
  float4 b2 = *(const float4*)&s[i + 4];
  unsigned short o[8] = {f2b(a.x),  f2b(a.y),  f2b(a.z),  f2b(a.w),
                         f2b(b2.x), f2b(b2.y), f2b(b2.z), f2b(b2.w)};
  *(uint4*)&d[i] = *(const uint4*)o;
}

// ---------------- QKV projection GEMM ----------------
// z==0 (Q) output pre-scaled by DH^-0.5 * log2(e) for the exp2-domain softmax.
// z==2 writes V transposed [bh][dh][n].
template <int AFP32>
__global__ __launch_bounds__(256) void gemm_qkv(
    const void* A0, const void* A1, const void* A2,
    const unsigned short* Wt,
    const float* b0, const float* b1, const float* b2,
    unsigned short* dQ, unsigned short* dK, unsigned short* dVt) {
  __shared__ unsigned short Al[128 * 32];
  __shared__ unsigned short Bl[128 * 32];
  const int t = threadIdx.x, z = blockIdx.z;
  const int m0 = blockIdx.y * 128, n0 = blockIdx.x * 128;
  const unsigned short* Bsrc = Wt + (size_t)z * WT_ONE;
  const void* Av = (z == 0) ? A0 : (z == 1) ? A1 : A2;
  const float* bias = (z == 0) ? b0 : (z == 1) ? b1 : b2;
  const int w = t >> 6, l = t & 63, lr = l & 15, lg = l >> 4;
  const int wm = (w >> 1) * 64, wn = (w & 1) * 64;

  f32x4 acc[4][4];
  #pragma unroll
  for (int i = 0; i < 4; i++)
    #pragma unroll
    for (int j = 0; j < 4; j++) acc[i][j] = (f32x4){0.f, 0.f, 0.f, 0.f};

  for (int k0 = 0; k0 < DD; k0 += 32) {
    __syncthreads();
    if (AFP32) {
      const float* Af = (const float*)Av;
      #pragma unroll
      for (int i = 0; i < 4; i++) {
        int row = i * 32 + (t >> 3), kk = 4 * (t & 7);
        float4 vv = *(const float4*)&Af[(size_t)(m0 + row) * DD + k0 + kk];
        ushort4 o4 = make_ushort4(f2b(vv.x), f2b(vv.y), f2b(vv.z), f2b(vv.w));
        *(ushort4*)&Al[row * 32 + kk] = o4;
      }
    } else {
      const unsigned short* Ab = (const unsigned short*)Av;
      #pragma unroll
      for (int c = 0; c < 2; c++)
        GLOAD16(&Ab[(size_t)(m0 + w * 32 + c * 16 + (l >> 2)) * DD + k0 + (l & 3) * 8],
                &Al[(w * 32 + c * 16) * 32]);
    }
    #pragma unroll
    for (int c = 0; c < 2; c++)
      GLOAD16(&Bsrc[(size_t)(n0 + w * 32 + c * 16 + (l >> 2)) * DD + k0 + (l & 3) * 8],
              &Bl[(w * 32 + c * 16) * 32]);
    __syncthreads();

    bf16x8 af[4], bfr[4];
    #pragma unroll
    for (int mi = 0; mi < 4; mi++)
      af[mi] = *(const bf16x8*)&Al[(wm + mi * 16 + lr) * 32 + lg * 8];
    #pragma unroll
    for (int ni = 0; ni < 4; ni++)
      bfr[ni] = *(const bf16x8*)&Bl[(wn + ni * 16 + lr) * 32 + lg * 8];
    #pragma unroll
    for (int mi = 0; mi < 4; mi++)
      #pragma unroll
      for (int ni = 0; ni < 4; ni++)
        acc[mi][ni] = __builtin_amdgcn_mfma_f32_16x16x32_bf16(
            af[mi], bfr[ni], acc[mi][ni], 0, 0, 0);
  }

  const float scl = (z == 0) ? SCLOG2E : 1.0f;
  #pragma unroll
  for (int mi = 0; mi < 4; mi++) {
    #pragma unroll
    for (int ni = 0; ni < 4; ni++) {
      int col = n0 + wn + ni * 16 + lr;
      float bv = bias[col];
      int h = col >> 6, dh = col & 63;
      int mbase = m0 + wm + mi * 16 + lg * 4;
      if (z == 2) {
        int bq = mbase >> 11, n = mbase & 2047;
        unsigned short o4[4];
        #pragma unroll
        for (int r = 0; r < 4; r++) o4[r] = f2b(acc[mi][ni][r] + bv);
        *(ushort4*)&dVt[(((size_t)(bq * HH + h)) * DH + dh) * NN + n] =
            *(const ushort4*)o4;
      } else {
        unsigned short* dst = (z == 0) ? dQ : dK;
        #pragma unroll
        for (int r = 0; r < 4; r++) {
          int m = mbase + r;
          int bq = m >> 11, n = m & 2047;
          dst[(((size_t)(bq * HH + h)) * NN + n) * DH + dh] =
              f2b((acc[mi][ni][r] + bv) * scl);
        }
      }
    }
  }
}

// ---------------- output projection GEMM ----------------
__global__ __launch_bounds__(256) void gemm_proj(
    const unsigned short* X, const unsigned short* Wt, const float* bias,
    float* out) {
  __shared__ unsigned short Al[128 * 32];
  __shared__ unsigned short Bl[128 * 32];
  const int t = threadIdx.x;
  const int m0 = blockIdx.y * 128, n0 = blockIdx.x * 128;
  const int w = t >> 6, l = t & 63, lr = l & 15, lg = l >> 4;
  const int wm = (w >> 1) * 64, wn = (w & 1) * 64;

  f32x4 acc[4][4];
  #pragma unroll
  for (int i = 0; i < 4; i++)
    #pragma unroll
    for (int j = 0; j < 4; j++) acc[i][j] = (f32x4){0.f, 0.f, 0.f, 0.f};

  for (int k0 = 0; k0 < DD; k0 += 32) {
    __syncthreads();
    #pragma unroll
    for (int c = 0; c < 2; c++) {
      GLOAD16(&X[(size_t)(m0 + w * 32 + c * 16 + (l >> 2)) * DD + k0 + (l & 3) * 8],
              &Al[(w * 32 + c * 16) * 32]);
      GLOAD16(&Wt[(size_t)(n0 + w * 32 + c * 16 + (l >> 2)) * DD + k0 + (l & 3) * 8],
              &Bl[(w * 32 + c * 16) * 32]);
    }
    __syncthreads();

    bf16x8 af[4], bfr[4];
    #pragma unroll
    for (int mi = 0; mi < 4; mi++)
      af[mi] = *(const bf16x8*)&Al[(wm + mi * 16 + lr) * 32 + lg * 8];
    #pragma unroll
    for (int ni = 0; ni < 4; ni++)
      bfr[ni] = *(const bf16x8*)&Bl[(wn + ni * 16 + lr) * 32 + lg * 8];
    #pragma unroll
    for (int mi = 0; mi < 4; mi++)
      #pragma unroll
      for (int ni = 0; ni < 4; ni++)
        acc[mi][ni] = __builtin_amdgcn_mfma_f32_16x16x32_bf16(
            af[mi], bfr[ni], acc[mi][ni], 0, 0, 0);
  }

  #pragma unroll
  for (int mi = 0; mi < 4; mi++) {
    #pragma unroll
    for (int ni = 0; ni < 4; ni++) {
      int col = n0 + wn + ni * 16 + lr;
      float bv = bias[col];
      #pragma unroll
      for (int r = 0; r < 4; r++) {
        int m = m0 + wm + mi * 16 + lg * 4 + r;
        out[(size_t)m * DD + col] = acc[mi][ni][r] + bv;
      }
    }
  }
}

// ---------------- flash attention: barrier-free, 1 wave / 32 q-rows ----------------
// S^T = mfma(K, Q): lane (lr,lg) owns q-row lr (per qi half), k-slots 16f+4lg+r.
// K/V fragments read directly from global (L2/L3 resident, coalesced b128).
__global__ __launch_bounds__(64) void attn_k(
    const unsigned short* qh, const unsigned short* kh,
    const unsigned short* vht, const unsigned long long* packed,
    unsigned short* x) {
  __shared__ __align__(16) char Pl[2][2][16 * 128];  // [parity][qi][q16 x k64 bf16]
  const int l = threadIdx.x, lr = l & 15, lg = l >> 4;
  const int q0 = blockIdx.x * 32, h = blockIdx.y, b = blockIdx.z;
  const size_t bh = (size_t)b * HH + h;
  const unsigned short* Q = qh + bh * (size_t)NN * DH;
  const unsigned short* K = kh + bh * (size_t)NN * DH;
  const unsigned short* V = vht + bh * (size_t)NN * DH;  // [dh][n]
  const int sw = (lr & 7) << 4;                          // XOR swizzle for P strip

  const unsigned long long* pm[2] = {
      packed + ((size_t)b * NN + q0 + lr) * (NN / 64),
      packed + ((size_t)b * NN + q0 + 16 + lr) * (NN / 64)};

  bf16x8 qf[2][2];
  #pragma unroll
  for (int qi = 0; qi < 2; qi++)
    #pragma unroll
    for (int kc = 0; kc < 2; kc++)
      qf[qi][kc] =
          *(const bf16x8*)&Q[(size_t)(q0 + qi * 16 + lr) * DH + kc * 32 + lg * 8];

  f32x4 o[2][4];
  #pragma unroll
  for (int qi = 0; qi < 2; qi++)
    #pragma unroll
    for (int f = 0; f < 4; f++) o[qi][f] = (f32x4){0.f, 0.f, 0.f, 0.f};
  float mrun[2] = {-1e30f, -1e30f}, lsum[2] = {0.f, 0.f};

  auto tile = [&](int ktv, bf16x8 (&kf)[4][2], bf16x8 (&kfn)[4][2], int par) {
    // V fragments for this tile (consumed after softmax -> latency hidden)
    bf16x8 vf[4][2];
    #pragma unroll
    for (int f = 0; f < 4; f++) {
      const unsigned short* vp = &V[(size_t)(16 * f + lr) * NN + ktv * 64 + lg * 8];
      vf[f][0] = *(const bf16x8*)vp;
      vf[f][1] = *(const bf16x8*)(vp + 32);
    }
    // prefetch next tile's K fragments (overlaps softmax + PV)
    int pn = (ktv + 1 < NN / 64) ? ktv + 1 : NN / 64 - 1;
    #pragma unroll
    for (int f = 0; f < 4; f++) {
      const unsigned short* kp = &K[(size_t)(pn * 64 + 16 * f + lr) * DH + lg * 8];
      kfn[f][0] = *(const bf16x8*)kp;
      kfn[f][1] = *(const bf16x8*)(kp + 32);
    }
    unsigned long long mw[2] = {pm[0][ktv], pm[1][ktv]};

    // S^T = K · Q (exp2 domain; Q pre-scaled by DH^-0.5*log2e)
    f32x4 s[2][4];
    #pragma unroll
    for (int f = 0; f < 4; f++) {
      f32x4 a = (f32x4){0.f, 0.f, 0.f, 0.f};
      a = __builtin_amdgcn_mfma_f32_16x16x32_bf16(kf[f][0], qf[0][0], a, 0, 0, 0);
      a = __builtin_amdgcn_mfma_f32_16x16x32_bf16(kf[f][1], qf[0][1], a, 0, 0, 0);
      s[0][f] = a;
      f32x4 c = (f32x4){0.f, 0.f, 0.f, 0.f};
      c = __builtin_amdgcn_mfma_f32_16x16x32_bf16(kf[f][0], qf[1][0], c, 0, 0, 0);
      c = __builtin_amdgcn_mfma_f32_16x16x32_bf16(kf[f][1], qf[1][1], c, 0, 0, 0);
      s[1][f] = c;
    }

    #pragma unroll
    for (int qi = 0; qi < 2; qi++) {
      float su[4][4];
      float mx = -1e30f;
      #pragma unroll
      for (int f = 0; f < 4; f++)
        #pragma unroll
        for (int r = 0; r < 4; r++) {
          int kb = 16 * f + lg * 4 + r;
          float vv = ((mw[qi] >> kb) & 1ull) ? -1e30f : s[qi][f][r];
          su[f][r] = vv;
          mx = fmaxf(mx, vv);
        }
      mx = fmaxf(mx, __shfl_xor(mx, 16));
      mx = fmaxf(mx, __shfl_xor(mx, 32));
      if (__any(mx > mrun[qi] + 8.f)) {            // defer-max (log2 THR=8)
        float mnew = fmaxf(mrun[qi], mx);
        float sf = __builtin_amdgcn_exp2f(mrun[qi] - mnew);
        lsum[qi] *= sf;
        #pragma unroll
        for (int f = 0; f < 4; f++) o[qi][f] *= sf;
        mrun[qi] = mnew;
      }
      float rs = 0.f, p[4][4];
      #pragma unroll
      for (int f = 0; f < 4; f++)
        #pragma unroll
        for (int r = 0; r < 4; r++) {
          float pv = __builtin_amdgcn_exp2f(su[f][r] - mrun[qi]);  // masked -> 0
          p[f][r] = pv;
          rs += pv;
        }
      rs += __shfl_xor(rs, 16);
      rs += __shfl_xor(rs, 32);
      lsum[qi] += rs;
      #pragma unroll
      for (int f = 0; f < 4; f++) {
        unsigned w0, w1;
        asm("v_cvt_pk_bf16_f32 %0, %1, %2" : "=v"(w0) : "v"(p[f][0]), "v"(p[f][1]));
        asm("v_cvt_pk_bf16_f32 %0, %1, %2" : "=v"(w1) : "v"(p[f][2]), "v"(p[f][3]));
        int off = lr * 128 + ((32 * f + 8 * lg) ^ sw);
        *(uint2*)&Pl[par][qi][off] = make_uint2(w0, w1);
      }
    }
    asm volatile("s_waitcnt lgkmcnt(0)" ::: "memory");
    __builtin_amdgcn_sched_barrier(0);

    #pragma unroll
    for (int qi = 0; qi < 2; qi++) {
      bf16x8 pf0 = *(const bf16x8*)&Pl[par][qi][lr * 128 + ((lg * 16) ^ sw)];
      bf16x8 pf1 = *(const bf16x8*)&Pl[par][qi][lr * 128 + ((64 + lg * 16) ^ sw)];
      #pragma unroll
      for (int f = 0; f < 4; f++) {
        o[qi][f] = __builtin_amdgcn_mfma_f32_16x16x32_bf16(vf[f][0], pf0,
                                                           o[qi][f], 0, 0, 0);
        o[qi][f] = __builtin_amdgcn_mfma_f32_16x16x32_bf16(vf[f][1], pf1,
                                                           o[qi][f], 0, 0, 0);
      }
    }
  };

  bf16x8 kfA[4][2], kfB[4][2];
  #pragma unroll
  for (int f = 0; f < 4; f++) {
    const unsigned short* kp = &K[(size_t)(16 * f + lr) * DH + lg * 8];
    kfA[f][0] = *(const bf16x8*)kp;
    kfA[f][1] = *(const bf16x8*)(kp + 32);
  }

  for (int kt = 0; kt < NN / 64; kt += 2) {
    tile(kt, kfA, kfB, 0);
    tile(kt + 1, kfB, kfA, 1);
  }

  #pragma unroll
  for (int qi = 0; qi < 2; qi++) {
    float inv = 1.f / fmaxf(lsum[qi], 1e-30f);
    #pragma unroll
    for (int f = 0; f < 4; f++) {
      unsigned w0, w1;
      float a0 = o[qi][f][0] * inv, a1 = o[qi][f][1] * inv;
      float a2 = o[qi][f][2] * inv, a3 = o[qi][f][3] * inv;
      asm("v_cvt_pk_bf16_f32 %0, %1, %2" : "=v"(w0) : "v"(a0), "v"(a1));
      asm("v_cvt_pk_bf16_f32 %0, %1, %2" : "=v"(w1) : "v"(a2), "v"(a3));
      *(uint2*)&x[((size_t)b * NN + q0 + qi * 16 + lr) * DD + h * DH + 16 * f +
                  lg * 4] = make_uint2(w0, w1);
    }
  }
}

extern "C" void kernel_launch(void* const* d_in, const int* in_sizes, int n_in,
                              void* d_out, int out_size, void* d_ws, size_t ws_size,
                              hipStream_t stream) {
  const float* q  = (const float*)d_in[0];
  const float* k  = (const float*)d_in[1];
  const float* v  = (const float*)d_in[2];
  const void*  mk = d_in[3];
  const float* Wq = (const float*)d_in[4];
  const float* bq = (const float*)d_in[5];
  const float* Wk = (const float*)d_in[6];
  const float* bk = (const float*)d_in[7];
  const float* Wv = (const float*)d_in[8];
  const float* bv = (const float*)d_in[9];
  const float* Wp = (const float*)d_in[10];
  const float* bp = (const float*)d_in[11];
  float* out = (float*)d_out;
  char* ws = (char*)d_ws;

  unsigned int* flag = (unsigned int*)ws;
  unsigned long long* packed = (unsigned long long*)(ws + OFF_PACK);
  unsigned short* wt  = (unsigned short*)(ws + OFF_WT);
  unsigned short* qhp = (unsigned short*)(ws + OFF_QH);
  unsigned short* khp = (unsigned short*)(ws + OFF_KH);
  unsigned short* vht = (unsigned short*)(ws + OFF_VT);
  unsigned short* x   = (unsigned short*)(ws + OFF_X);
  unsigned short* qb  = (unsigned short*)(ws + OFF_X);  // alias: dead before attn
  unsigned short* kb  = (unsigned short*)(ws + OFF_KB);
  unsigned short* vb  = (unsigned short*)(ws + OFF_VB);

  const bool big = ws_size >= NEED_BIG;

  hipMemsetAsync(flag, 0, 4, stream);
  detect_mask<<<1, 256, 0, stream>>>((const unsigned int*)mk, flag);
  pack_mask<<<dim3(512), 256, 0, stream>>>(mk, flag, packed);
  transpose_w<<<dim3(16, 16, 4), 256, 0, stream>>>(Wq, Wk, Wv, Wp, wt);
  if (big) {
    cvt_qkv<<<dim3(2048, 1, 3), 256, 0, stream>>>(q, k, v, qb, kb, vb);
    gemm_qkv<0><<<dim3(8, 32, 3), 256, 0, stream>>>(qb, kb, vb, wt, bq, bk, bv,
                                                    qhp, khp, vht);
  } else {
    gemm_qkv<1><<<dim3(8, 32, 3), 256, 0, stream>>>(q, k, v, wt, bq, bk, bv,
                                                    qhp, khp, vht);
  }
  attn_k<<<dim3(NN / 32, HH, BB), 64, 0, stream>>>(qhp, khp, vht, packed, x);
  gemm_proj<<<dim3(8, 32), 256, 0, stream>>>(x, wt + 3 * WT_ONE, bp, out);
}